// Round 4
// baseline (678.438 us; speedup 1.0000x reference)
//
#include <hip/hip_runtime.h>

// Problem dims (fixed).
#define BB 512
#define TT 1024
#define DD 64
#define HH 64
#define BT (BB * TT)    // 524288
#define Y_SIZE (BB * TT * HH)  // 33554432

typedef _Float16 half8 __attribute__((ext_vector_type(8)));
typedef _Float16 half4 __attribute__((ext_vector_type(4)));
typedef float f32x4 __attribute__((ext_vector_type(4)));

#define MFMA16(a, b, c) __builtin_amdgcn_mfma_f32_16x16x32_f16((a), (b), (c), 0, 0, 0)

// Raw workgroup barrier draining ONLY lgkmcnt (LDS); y/outs stores and x
// prefetch loads stay in flight (R2: +2%). All cross-wave data is LDS.
__device__ __forceinline__ void wg_barrier_lds() {
    asm volatile("s_waitcnt lgkmcnt(0)" ::: "memory");
    __builtin_amdgcn_s_barrier();
    asm volatile("" ::: "memory");
}

__device__ __forceinline__ float sigm(float x) {
    return __builtin_amdgcn_rcpf(1.0f + __expf(-x));
}
__device__ __forceinline__ float tanh_(float x) {
    return 1.0f - 2.0f * __builtin_amdgcn_rcpf(1.0f + __expf(2.0f * x));
}

__device__ __forceinline__ half8 cvt8(f32x4 a, f32x4 b) {
    half8 h;
    h[0] = (_Float16)a[0]; h[1] = (_Float16)a[1];
    h[2] = (_Float16)a[2]; h[3] = (_Float16)a[3];
    h[4] = (_Float16)b[0]; h[5] = (_Float16)b[1];
    h[6] = (_Float16)b[2]; h[7] = (_Float16)b[3];
    return h;
}

// ---------------------------------------------------------------------------
// FUSED LSTM + heads: 256 WGs (2 batch rows each), 256 threads (4 waves).
// [R1: 2 WGs/CU regressed (duplicate-issue). R2: lgkm barrier +2%.
//  R3: x-part pipelining +2%. R4: heads_kernel (~247us, 44% of total) FUSED
//  into the step's ~25% idle issue slots — h(t) is already in hst LDS in
//  exactly the A-fragment layout heads L1 needs (reuses a2/a3 reads).]
// Heads pipeline (per wave, head = wave index; h1w is per-wave private):
//   step t: L1(h(t-1)=y[t-1]) via a2/a3 -> relu -> h1w[p]   (4 MFMA)
//           L2(h1w[p^1] = h1 of y[t-2]) -> relu             (2 MFMA)
//           L3 dot-32 via shfl_xor reduce -> outs row t-2   (~12 VALU)
//   h1w round trip needs no extra barrier: end-of-step lgkm drain covers it.
//   Epilogue emits rows T-2 and T-1.
// ---------------------------------------------------------------------------
__global__ __launch_bounds__(256) void lstm_fused_kernel(
    const float* __restrict__ x, const float* __restrict__ h_init,
    const float* __restrict__ c_init, const float* __restrict__ W_ih,
    const float* __restrict__ W_hh, const float* __restrict__ b_ih,
    const float* __restrict__ b_hh,
    const float* __restrict__ W1, const float* __restrict__ b1,
    const float* __restrict__ W2, const float* __restrict__ b2,
    const float* __restrict__ W3, const float* __restrict__ b3,
    float* __restrict__ y, float* __restrict__ outs)
{
    __shared__ alignas(16) _Float16 xch[2][16][2][DD];  // x chunks, f16, dbuf
    __shared__ alignas(16) _Float16 hst[2][2][HH];      // h stage, dbuf
    __shared__ alignas(16) _Float16 h1w[4][2][2][32];   // [wave][parity][batch][unit]

    const int tid  = threadIdx.x;
    const int wave = tid >> 6;
    const int lane = tid & 63;
    const int col  = lane & 15;
    const int quad = lane >> 4;
    const int sel  = (lane >> 3) & 1;       // batch row this lane feeds as A
    const int r_act = lane >> 5;            // batch row this lane's unit belongs to
    const int j    = (wave << 4) + col;     // hidden unit index [0,64)
    const bool writer = ((lane >> 4) & 1) == 0;  // quads 1,3 duplicate

    const int b0 = blockIdx.x * 2;

    // ---- gate weight fragments: B[k][n] = Wcat[n][k] (f16) ----
    half8 bf[4][4];
    f32x4 biasv[4];
#pragma unroll
    for (int G = 0; G < 4; ++G) {
        const int n = (G << 6) + j;
        const float bs = b_ih[n] + b_hh[n];
        biasv[G][0] = bs; biasv[G][1] = bs; biasv[G][2] = bs; biasv[G][3] = bs;
#pragma unroll
        for (int c = 0; c < 4; ++c) {
            const float* src = (c < 2) ? (W_ih + n * DD + c * 32 + quad * 8)
                                       : (W_hh + n * HH + (c - 2) * 32 + quad * 8);
            f32x4 w0 = *(const f32x4*)src;
            f32x4 w1 = *(const f32x4*)(src + 4);
            bf[G][c] = cvt8(w0, w1);
        }
    }

    // ---- heads weight fragments (head = wave) ----
    // L1: n = hd*32 + nt*16 + col over W1 flat (128 x 64); K chunks 0,1.
    // L2: same n over W2 flat (128 x 32); single K=32 chunk.
    half8 w1f[2][2]; f32x4 b1v[2];
    half8 w2f[2];    f32x4 b2v[2];
    float w3a, w3b, b3v;
    {
        const int hd = wave;
#pragma unroll
        for (int nt = 0; nt < 2; ++nt) {
            const int n = hd * 32 + nt * 16 + col;
            const float s1 = b1[n];
            b1v[nt][0] = s1; b1v[nt][1] = s1; b1v[nt][2] = s1; b1v[nt][3] = s1;
#pragma unroll
            for (int c = 0; c < 2; ++c) {
                const float* src = W1 + n * 64 + c * 32 + quad * 8;
                w1f[nt][c] = cvt8(*(const f32x4*)src, *(const f32x4*)(src + 4));
            }
            const float s2 = b2[n];
            b2v[nt][0] = s2; b2v[nt][1] = s2; b2v[nt][2] = s2; b2v[nt][3] = s2;
            const float* src2 = W2 + n * 32 + quad * 8;
            w2f[nt] = cvt8(*(const f32x4*)src2, *(const f32x4*)(src2 + 4));
        }
        w3a = W3[hd * 32 + col];
        w3b = W3[hd * 32 + 16 + col];
        b3v = b3[hd];
    }

    float c_state = c_init[j];

    // ---- init h stage (buffer 0), first x chunk, zero h1w ----
    if (tid < 128) {
        const int rr = tid >> 6, jj = tid & 63;
        hst[0][rr][jj] = (_Float16)h_init[jj];
    }
    {
        const int ss = tid >> 4, rr = (tid >> 3) & 1, j0 = (tid & 7) << 3;
        const float* src = x + ((b0 + rr) * TT + ss) * DD + j0;
        f32x4 g0 = *(const f32x4*)src;
        f32x4 g1 = *(const f32x4*)(src + 4);
        *(half8*)&xch[0][ss][rr][j0] = cvt8(g0, g1);
    }
    ((unsigned int*)h1w)[tid] = 0u;  // 256 dwords = entire h1w
    wg_barrier_lds();

    const int ss_pf = tid >> 4, rr_pf = (tid >> 3) & 1, j0_pf = (tid & 7) << 3;

    // ---- x-part pipeline prologue: xacc for t=0 ----
    f32x4 xacc0, xacc1, xacc2, xacc3;
    {
        const _Float16* xrow = &xch[0][0][sel][0];
        half8 a0 = *(const half8*)(xrow + quad * 8);
        half8 a1 = *(const half8*)(xrow + 32 + quad * 8);
        xacc0 = MFMA16(a0, bf[0][0], biasv[0]); xacc0 = MFMA16(a1, bf[0][1], xacc0);
        xacc1 = MFMA16(a0, bf[1][0], biasv[1]); xacc1 = MFMA16(a1, bf[1][1], xacc1);
        xacc2 = MFMA16(a0, bf[2][0], biasv[2]); xacc2 = MFMA16(a1, bf[2][1], xacc2);
        xacc3 = MFMA16(a0, bf[3][0], biasv[3]); xacc3 = MFMA16(a1, bf[3][1], xacc3);
    }

    const long outs_base = (long)wave * BT + (b0 + (lane >> 5)) * (long)TT;

    for (int ci = 0; ci < 64; ++ci) {
        const int buf = ci & 1;
        const bool pf = (ci + 1) < 64;
        f32x4 g0, g1;
        if (pf) {  // prefetch next 16-step x chunk (lands at s==14)
            const float* src = x + ((b0 + rr_pf) * TT + ((ci + 1) << 4) + ss_pf) * DD + j0_pf;
            g0 = *(const f32x4*)src;
            g1 = *(const f32x4*)(src + 4);
        }
#pragma unroll
        for (int s = 0; s < 16; ++s) {
            const int t = (ci << 4) + s;
            const int p = s & 1;

            // A fragments: h(t-1) from h stage (also heads-L1 input = y[t-1])
            const _Float16* hrow = &hst[p][sel][0];
            half8 a2 = *(const half8*)(hrow + quad * 8);
            half8 a3 = *(const half8*)(hrow + 32 + quad * 8);
            // heads-L2 input: h1 of y[t-2] (per-wave private slot)
            const _Float16* h1p = &h1w[wave][p ^ 1][sel][0];
            half8 ah = *(const half8*)(h1p + quad * 8);

            // gate h-part: 2-deep chain on precomputed xacc [critical]
            f32x4 acc0 = MFMA16(a2, bf[0][2], xacc0);
            f32x4 acc1 = MFMA16(a2, bf[1][2], xacc1);
            f32x4 acc2 = MFMA16(a2, bf[2][2], xacc2);
            f32x4 acc3 = MFMA16(a2, bf[3][2], xacc3);
            acc0 = MFMA16(a3, bf[0][3], acc0); acc1 = MFMA16(a3, bf[1][3], acc1);
            acc2 = MFMA16(a3, bf[2][3], acc2); acc3 = MFMA16(a3, bf[3][3], acc3);

            // heads L2 (independent of gate chain)
            f32x4 h2a = MFMA16(ah, w2f[0], b2v[0]);
            f32x4 h2b = MFMA16(ah, w2f[1], b2v[1]);
            // heads L1 on y[t-1] (reuses a2/a3; at t=0 input is h_init ->
            // result discarded via the t>=2 store guard two steps later)
            f32x4 p1a = MFMA16(a2, w1f[0][0], b1v[0]); p1a = MFMA16(a3, w1f[0][1], p1a);
            f32x4 p1b = MFMA16(a2, w1f[1][0], b1v[1]); p1b = MFMA16(a3, w1f[1][1], p1b);

            // next step's x-part (independent; fills matrix pipe under VALU)
            if (t < TT - 1) {
                const _Float16* nx = (s < 15) ? &xch[buf][s + 1][sel][0]
                                              : &xch[buf ^ 1][0][sel][0];
                half8 a0 = *(const half8*)(nx + quad * 8);
                half8 a1 = *(const half8*)(nx + 32 + quad * 8);
                xacc0 = MFMA16(a0, bf[0][0], biasv[0]); xacc0 = MFMA16(a1, bf[0][1], xacc0);
                xacc1 = MFMA16(a0, bf[1][0], biasv[1]); xacc1 = MFMA16(a1, bf[1][1], xacc1);
                xacc2 = MFMA16(a0, bf[2][0], biasv[2]); xacc2 = MFMA16(a1, bf[2][1], xacc2);
                xacc3 = MFMA16(a0, bf[3][0], biasv[3]); xacc3 = MFMA16(a1, bf[3][1], xacc3);
            }

            // heads L3: out = relu(h2) . W3 + b3, reduced across the 16-lane
            // group (quads 0,1 = batch0 dup; 2,3 = batch1 dup) -> row t-2
            {
                float v0 = fmaxf(h2a[0], 0.0f);
                float v1 = fmaxf(h2b[0], 0.0f);
                float part = v0 * w3a + v1 * w3b;
                part += __shfl_xor(part, 1);
                part += __shfl_xor(part, 2);
                part += __shfl_xor(part, 4);
                part += __shfl_xor(part, 8);
                if (t >= 2 && (lane & 31) == 0)
                    outs[outs_base + (t - 2)] = part + b3v;
            }
            // heads L1 write: lane(q,c) -> h1w[p][q>>1][(q&1)*16+c]
            h1w[wave][p][quad >> 1][((quad & 1) << 4) + col] =
                (_Float16)fmaxf(((quad & 1) ? p1b : p1a)[0], 0.0f);

            // LSTM activation: D reg0 -> (batch r_act, unit j)
            const float si = sigm(acc0[0]);
            const float sf = sigm(acc1[0]);
            const float tg = tanh_(acc2[0]);
            const float so = sigm(acc3[0]);
            c_state = sf * c_state + si * tg;
            const float hv = so * tanh_(c_state);
            if (writer) {
                hst[p ^ 1][r_act][j] = (_Float16)hv;
                y[((b0 + r_act) * TT + t) * HH + j] = hv;  // in flight across barrier
            }
            if (s == 14 && pf) {  // land prefetched chunk
                *(half8*)&xch[buf ^ 1][ss_pf][rr_pf][j0_pf] = cvt8(g0, g1);
            }
            wg_barrier_lds();  // lgkm-only; also publishes h1w round trip
        }
    }

    // ---- heads epilogue: rows TT-2 (from h1w[1]) and TT-1 (from hst[0]) ----
    {
        // row TT-2: h1 of y[TT-2] sits in h1w[1] (written at t=1023, p=1)
        const _Float16* h1p = &h1w[wave][1][sel][0];
        half8 ah = *(const half8*)(h1p + quad * 8);
        f32x4 h2a = MFMA16(ah, w2f[0], b2v[0]);
        f32x4 h2b = MFMA16(ah, w2f[1], b2v[1]);
        float part = fmaxf(h2a[0], 0.0f) * w3a + fmaxf(h2b[0], 0.0f) * w3b;
        part += __shfl_xor(part, 1);
        part += __shfl_xor(part, 2);
        part += __shfl_xor(part, 4);
        part += __shfl_xor(part, 8);
        if ((lane & 31) == 0) outs[outs_base + (TT - 2)] = part + b3v;

        // row TT-1: y[TT-1] = h(T-1) sits in hst[0] (written at t=1023)
        const _Float16* hrow = &hst[0][sel][0];
        half8 a2 = *(const half8*)(hrow + quad * 8);
        half8 a3 = *(const half8*)(hrow + 32 + quad * 8);
        f32x4 p1a = MFMA16(a2, w1f[0][0], b1v[0]); p1a = MFMA16(a3, w1f[0][1], p1a);
        f32x4 p1b = MFMA16(a2, w1f[1][0], b1v[1]); p1b = MFMA16(a3, w1f[1][1], p1b);
        h1w[wave][0][quad >> 1][((quad & 1) << 4) + col] =
            (_Float16)fmaxf(((quad & 1) ? p1b : p1a)[0], 0.0f);
        asm volatile("s_waitcnt lgkmcnt(0)" ::: "memory");  // same-wave round trip
        const _Float16* h1q = &h1w[wave][0][sel][0];
        half8 ah2 = *(const half8*)(h1q + quad * 8);
        f32x4 q2a = MFMA16(ah2, w2f[0], b2v[0]);
        f32x4 q2b = MFMA16(ah2, w2f[1], b2v[1]);
        float part2 = fmaxf(q2a[0], 0.0f) * w3a + fmaxf(q2b[0], 0.0f) * w3b;
        part2 += __shfl_xor(part2, 1);
        part2 += __shfl_xor(part2, 2);
        part2 += __shfl_xor(part2, 4);
        part2 += __shfl_xor(part2, 8);
        if ((lane & 31) == 0) outs[outs_base + (TT - 1)] = part2 + b3v;
    }
}

extern "C" void kernel_launch(void* const* d_in, const int* in_sizes, int n_in,
                              void* d_out, int out_size, void* d_ws, size_t ws_size,
                              hipStream_t stream) {
    (void)in_sizes; (void)n_in; (void)out_size; (void)d_ws; (void)ws_size;
    const float* x      = (const float*)d_in[0];
    const float* h_init = (const float*)d_in[1];
    const float* c_init = (const float*)d_in[2];
    const float* W_ih   = (const float*)d_in[3];
    const float* W_hh   = (const float*)d_in[4];
    const float* b_ih   = (const float*)d_in[5];
    const float* b_hh   = (const float*)d_in[6];
    const float* W1     = (const float*)d_in[7];
    const float* b1     = (const float*)d_in[8];
    const float* W2     = (const float*)d_in[9];
    const float* b2     = (const float*)d_in[10];
    const float* W3     = (const float*)d_in[11];
    const float* b3     = (const float*)d_in[12];
    float* y    = (float*)d_out;
    float* outs = y + Y_SIZE;

    lstm_fused_kernel<<<dim3(256), dim3(256), 0, stream>>>(
        x, h_init, c_init, W_ih, W_hh, b_ih, b_hh,
        W1, b1, W2, b2, W3, b3, y, outs);
}

// Round 5
// 567.307 us; speedup vs baseline: 1.1959x; 1.1959x over previous
//
#include <hip/hip_runtime.h>

// Problem dims (fixed).
#define BB 512
#define TT 1024
#define DD 64
#define HH 64
#define BT (BB * TT)    // 524288
#define Y_SIZE (BB * TT * HH)  // 33554432

typedef _Float16 half8 __attribute__((ext_vector_type(8)));
typedef _Float16 half4 __attribute__((ext_vector_type(4)));
typedef float f32x4 __attribute__((ext_vector_type(4)));

#define MFMA16(a, b, c) __builtin_amdgcn_mfma_f32_16x16x32_f16((a), (b), (c), 0, 0, 0)

// Raw workgroup barrier draining ONLY lgkmcnt (LDS); y stores and x prefetch
// loads stay in flight (R2: +2%). All cross-wave data is LDS.
__device__ __forceinline__ void wg_barrier_lds() {
    asm volatile("s_waitcnt lgkmcnt(0)" ::: "memory");
    __builtin_amdgcn_s_barrier();
    asm volatile("" ::: "memory");
}

__device__ __forceinline__ float sigm(float x) {
    return __builtin_amdgcn_rcpf(1.0f + __expf(-x));
}
__device__ __forceinline__ float tanh_(float x) {
    return 1.0f - 2.0f * __builtin_amdgcn_rcpf(1.0f + __expf(2.0f * x));
}

__device__ __forceinline__ half8 cvt8(f32x4 a, f32x4 b) {
    half8 h;
    h[0] = (_Float16)a[0]; h[1] = (_Float16)a[1];
    h[2] = (_Float16)a[2]; h[3] = (_Float16)a[3];
    h[4] = (_Float16)b[0]; h[5] = (_Float16)b[1];
    h[6] = (_Float16)b[2]; h[7] = (_Float16)b[3];
    return h;
}

// ---------------------------------------------------------------------------
// LSTM kernel: 256 WGs (2 batch rows each), 256 threads (4 waves), 1 WG/CU.
// [R1: 2 WGs/CU regressed. R2: lgkm barrier +2%. R3: x-pipelining +2%.
//  R4: fusion regressed (no idle issue slots at 1 wave/SIMD).
//  R5: xg-HOIST — the 8 per-step x-part MFMAs (A replicated 8x, 1/8 useful)
//  are replaced by a per-chunk burst of 16 full MFMAs (A rows = 16 timesteps)
//  producing xg[s][rr][gate] in LDS. 1 MFMA/step amortized instead of 8/step.
//  Each wave writes and reads only its own gate columns -> no extra barrier;
//  f32 LDS round trip is bit-exact vs the chained-C version.]
// Per step now: read 4 xg scalars + h A-frags, 8 h-MFMAs (2-deep), activation,
// h write, ONE lgkm-only barrier.
// ---------------------------------------------------------------------------
__global__ __launch_bounds__(256) void lstm_kernel(
    const float* __restrict__ x, const float* __restrict__ h_init,
    const float* __restrict__ c_init, const float* __restrict__ W_ih,
    const float* __restrict__ W_hh, const float* __restrict__ b_ih,
    const float* __restrict__ b_hh, float* __restrict__ y)
{
    // xch inner dim padded 64->72 halves: the burst's A-frag reads (rows = s)
    // would otherwise be 16-way bank-conflicted (256B row stride).
    __shared__ alignas(16) _Float16 xch[2][16][2][72];  // x chunks, f16, dbuf
    __shared__ alignas(16) _Float16 hst[2][2][HH];      // h stage, dbuf
    // xg inner stride 265 dwords (not 264/256): makes burst writes ~2-way
    // (530%8==2 so quad spreads banks) and per-step reads ~2-way. ~34 KB.
    __shared__ float xg[16][2][265];                    // per-chunk x-gates, f32

    const int tid  = threadIdx.x;
    const int wave = tid >> 6;
    const int lane = tid & 63;
    const int col  = lane & 15;
    const int quad = lane >> 4;
    const int sel  = (lane >> 3) & 1;       // batch row this lane feeds as A
    const int r_act = lane >> 5;            // batch row this lane's unit belongs to
    const int j    = (wave << 4) + col;     // hidden unit index [0,64)
    const bool writer = ((lane >> 4) & 1) == 0;  // quads 1,3 duplicate

    const int b0 = blockIdx.x * 2;

    // ---- resident weight fragments: B[k][n] = Wcat[n][k] (f16) ----
    // n = 64*G + j ; k chunks: 0,1 -> W_ih, 2,3 -> W_hh
    half8 bf[4][4];
    f32x4 biasv[4];
#pragma unroll
    for (int G = 0; G < 4; ++G) {
        const int n = (G << 6) + j;
        const float bs = b_ih[n] + b_hh[n];
        biasv[G][0] = bs; biasv[G][1] = bs; biasv[G][2] = bs; biasv[G][3] = bs;
#pragma unroll
        for (int c = 0; c < 4; ++c) {
            const float* src = (c < 2) ? (W_ih + n * DD + c * 32 + quad * 8)
                                       : (W_hh + n * HH + (c - 2) * 32 + quad * 8);
            f32x4 w0 = *(const f32x4*)src;
            f32x4 w1 = *(const f32x4*)(src + 4);
            bf[G][c] = cvt8(w0, w1);
        }
    }

    float c_state = c_init[j];

    // ---- init h stage (buffer 0) + first x chunk ----
    if (tid < 128) {
        const int rr = tid >> 6, jj = tid & 63;
        hst[0][rr][jj] = (_Float16)h_init[jj];
    }
    {
        const int ss = tid >> 4, rr = (tid >> 3) & 1, j0 = (tid & 7) << 3;
        const float* src = x + ((b0 + rr) * TT + ss) * DD + j0;
        f32x4 g0 = *(const f32x4*)src;
        f32x4 g1 = *(const f32x4*)(src + 4);
        *(half8*)&xch[0][ss][rr][j0] = cvt8(g0, g1);
    }
    wg_barrier_lds();

    const int ss_pf = tid >> 4, rr_pf = (tid >> 3) & 1, j0_pf = (tid & 7) << 3;

    for (int ci = 0; ci < 64; ++ci) {
        const int buf = ci & 1;
        const bool pf = (ci + 1) < 64;
        f32x4 g0, g1;
        if (pf) {  // prefetch next 16-step x chunk (lands at s==14)
            const float* src = x + ((b0 + rr_pf) * TT + ((ci + 1) << 4) + ss_pf) * DD + j0_pf;
            g0 = *(const f32x4*)src;
            g1 = *(const f32x4*)(src + 4);
        }

        // ---- xg burst: xg[s][rr][G*64+j] = bias + x_s . W_ih[gate] ----
        // A rows = 16 timesteps (full MFMA utilization). Wave-self-contained:
        // this wave only ever reads back gate columns j it wrote itself, so
        // only same-wave lgkm ordering (compiler-inserted) is needed.
#pragma unroll
        for (int rr = 0; rr < 2; ++rr) {
            half8 ax0 = *(const half8*)&xch[buf][col][rr][quad * 8];
            half8 ax1 = *(const half8*)&xch[buf][col][rr][32 + quad * 8];
#pragma unroll
            for (int G = 0; G < 4; ++G) {
                f32x4 d = MFMA16(ax0, bf[G][0], biasv[G]);
                d = MFMA16(ax1, bf[G][1], d);
#pragma unroll
                for (int r = 0; r < 4; ++r)
                    xg[(quad << 2) + r][rr][(G << 6) + j] = d[r];
            }
        }

#pragma unroll
        for (int s = 0; s < 16; ++s) {
            const int t = (ci << 4) + s;
            const int p = s & 1;

            // this step's x-gate pre-acts (scalars; only D reg0 is consumed,
            // and MFMA rows are independent, so C[1..3] may be garbage)
            const float xg0 = xg[s][r_act][0 * 64 + j];
            const float xg1 = xg[s][r_act][1 * 64 + j];
            const float xg2 = xg[s][r_act][2 * 64 + j];
            const float xg3 = xg[s][r_act][3 * 64 + j];
            // h A-frags
            const _Float16* hrow = &hst[p][sel][0];
            half8 a2 = *(const half8*)(hrow + quad * 8);
            half8 a3 = *(const half8*)(hrow + 32 + quad * 8);

            f32x4 c0 = {xg0, xg0, xg0, xg0};
            f32x4 c1 = {xg1, xg1, xg1, xg1};
            f32x4 c2 = {xg2, xg2, xg2, xg2};
            f32x4 c3 = {xg3, xg3, xg3, xg3};
            f32x4 acc0 = MFMA16(a2, bf[0][2], c0);
            f32x4 acc1 = MFMA16(a2, bf[1][2], c1);
            f32x4 acc2 = MFMA16(a2, bf[2][2], c2);
            f32x4 acc3 = MFMA16(a2, bf[3][2], c3);
            acc0 = MFMA16(a3, bf[0][3], acc0); acc1 = MFMA16(a3, bf[1][3], acc1);
            acc2 = MFMA16(a3, bf[2][3], acc2); acc3 = MFMA16(a3, bf[3][3], acc3);

            // activation: D reg0 -> (batch r_act, unit j)
            const float si = sigm(acc0[0]);
            const float sf = sigm(acc1[0]);
            const float tg = tanh_(acc2[0]);
            const float so = sigm(acc3[0]);
            c_state = sf * c_state + si * tg;
            const float hv = so * tanh_(c_state);
            if (writer) {
                hst[p ^ 1][r_act][j] = (_Float16)hv;
                y[((b0 + r_act) * TT + t) * HH + j] = hv;  // in flight across barrier
            }
            if (s == 14 && pf) {  // land prefetched chunk (published at s14 barrier)
                *(half8*)&xch[buf ^ 1][ss_pf][rr_pf][j0_pf] = cvt8(g0, g1);
            }
            wg_barrier_lds();  // lgkm-only: hst/xch visible; y stores NOT drained
        }
    }
}

// ---------------------------------------------------------------------------
// Heads v2: 2048 WGs x 256 threads, ZERO barriers. Each wave independently
// processes 4 tiles of 16 rows (WG covers 256 rows). A-frags loaded straight
// from global y (no ybuf staging), one-tile register prefetch. L1/L2 are the
// proven MFMA paths writing per-wave parity-rotated LDS transpose buffers
// (same-wave in-order DS + compiler lgkm waits; no s_barrier). L3 is a
// 4-MFMA block-diagonal matmul with W3 as a mostly-zero B-fragment ->
// f32x4 vector stores. Old version: 16 WG barriers + staged LDS ~ 110us.
// ---------------------------------------------------------------------------
__global__ __launch_bounds__(256) void heads_kernel(
    const float* __restrict__ y,
    const float* __restrict__ W1, const float* __restrict__ b1,
    const float* __restrict__ W2, const float* __restrict__ b2,
    const float* __restrict__ W3, const float* __restrict__ b3,
    float* __restrict__ outs)
{
    // stride 144 halves (288B): h1 reads land ~2-way on banks.
    __shared__ alignas(16) _Float16 h1w[4][2][16][144];  // [wave][tile parity]
    __shared__ alignas(16) _Float16 h2w[4][2][16][144];

    const int tid  = threadIdx.x;
    const int wave = tid >> 6;
    const int lane = tid & 63;
    const int col  = lane & 15;
    const int quad = lane >> 4;

    // W1 fragments: 8 N-tiles x 2 K-chunks (W1 flat 128x64).
    half8 w1f[8][2]; float bias1[8];
#pragma unroll
    for (int nt = 0; nt < 8; ++nt) {
        const int n = nt * 16 + col;
        bias1[nt] = b1[n];
#pragma unroll
        for (int c = 0; c < 2; ++c) {
            const float* src = W1 + n * 64 + c * 32 + quad * 8;
            w1f[nt][c] = cvt8(*(const f32x4*)src, *(const f32x4*)(src + 4));
        }
    }
    // W2 fragments: 8 N-tiles (head = nt>>1), single K=32 chunk (flat 128x32).
    half8 w2f[8]; float bias2[8];
#pragma unroll
    for (int nt = 0; nt < 8; ++nt) {
        const int n = nt * 16 + col;
        bias2[nt] = b2[n];
        const float* src = W2 + n * 32 + quad * 8;
        w2f[nt] = cvt8(*(const f32x4*)src, *(const f32x4*)(src + 4));
    }
    // W3 as block-diagonal B-fragment over K=128: B[k][n]=W3[n][k-32n] for
    // k in [32n,32n+32), else 0. Lane col=n holds nonzero only in chunk kc==col.
    half8 b3f[4];
    {
        const float* src = W3 + (col < 4 ? col * 32 : 0) + quad * 8;
        half8 wv = cvt8(*(const f32x4*)src, *(const f32x4*)(src + 4));
        half8 hz;
#pragma unroll
        for (int i = 0; i < 8; ++i) hz[i] = (_Float16)0.0f;
#pragma unroll
        for (int kc = 0; kc < 4; ++kc)
            b3f[kc] = (col == kc) ? wv : hz;
    }
    const float b3v = (col < 4) ? b3[col] : 0.0f;

    const long wbase = (long)blockIdx.x * 256 + wave * 64;  // wave's 64 rows

    // prefetch tile 0 A-operand (16 rows x 64 cols f32; this lane: row col,
    // k slices quad*8..+8 and 32+quad*8..+8)
    f32x4 ga0, ga1, ga2, ga3;
    {
        const float* src = y + (wbase + col) * 64 + quad * 8;
        ga0 = *(const f32x4*)src;       ga1 = *(const f32x4*)(src + 4);
        ga2 = *(const f32x4*)(src + 32); ga3 = *(const f32x4*)(src + 36);
    }

#pragma unroll
    for (int tb = 0; tb < 4; ++tb) {
        const int pb = tb & 1;
        half8 a0 = cvt8(ga0, ga1);
        half8 a1 = cvt8(ga2, ga3);
        if (tb < 3) {  // prefetch next tile (hidden under this tile's compute)
            const float* src = y + (wbase + (tb + 1) * 16 + col) * 64 + quad * 8;
            ga0 = *(const f32x4*)src;       ga1 = *(const f32x4*)(src + 4);
            ga2 = *(const f32x4*)(src + 32); ga3 = *(const f32x4*)(src + 36);
        }

        // L1: h1 = relu(y @ W1^T + b1) -> per-wave transpose buffer
#pragma unroll
        for (int nt = 0; nt < 8; ++nt) {
            f32x4 acc = {bias1[nt], bias1[nt], bias1[nt], bias1[nt]};
            acc = MFMA16(a0, w1f[nt][0], acc);
            acc = MFMA16(a1, w1f[nt][1], acc);
#pragma unroll
            for (int r = 0; r < 4; ++r) {
                float v = acc[r] > 0.0f ? acc[r] : 0.0f;
                h1w[wave][pb][(quad << 2) + r][nt * 16 + col] = (_Float16)v;
            }
        }
        // L2: h2 = relu(h1 @ W2^T + b2), block-diagonal per head
        half8 ah[4];
#pragma unroll
        for (int hd = 0; hd < 4; ++hd)
            ah[hd] = *(const half8*)&h1w[wave][pb][col][hd * 32 + quad * 8];
#pragma unroll
        for (int nt = 0; nt < 8; ++nt) {
            f32x4 acc = {bias2[nt], bias2[nt], bias2[nt], bias2[nt]};
            acc = MFMA16(ah[nt >> 1], w2f[nt], acc);
#pragma unroll
            for (int r = 0; r < 4; ++r) {
                float v = acc[r] > 0.0f ? acc[r] : 0.0f;
                h2w[wave][pb][(quad << 2) + r][nt * 16 + col] = (_Float16)v;
            }
        }
        // L3: out[row][hd] = relu(h2[row]) . W3_blockdiag + b3 via 4 MFMA
        f32x4 d = {b3v, b3v, b3v, b3v};
#pragma unroll
        for (int kc = 0; kc < 4; ++kc) {
            half8 av = *(const half8*)&h2w[wave][pb][col][kc * 32 + quad * 8];
            d = MFMA16(av, b3f[kc], d);
        }
        // D: col = head, rows quad*4+r -> 4 consecutive rows: f32x4 store
        if (col < 4)
            *(f32x4*)(outs + (long)col * BT + wbase + tb * 16 + quad * 4) = d;
    }
}

extern "C" void kernel_launch(void* const* d_in, const int* in_sizes, int n_in,
                              void* d_out, int out_size, void* d_ws, size_t ws_size,
                              hipStream_t stream) {
    (void)in_sizes; (void)n_in; (void)out_size; (void)d_ws; (void)ws_size;
    const float* x      = (const float*)d_in[0];
    const float* h_init = (const float*)d_in[1];
    const float* c_init = (const float*)d_in[2];
    const float* W_ih   = (const float*)d_in[3];
    const float* W_hh   = (const float*)d_in[4];
    const float* b_ih   = (const float*)d_in[5];
    const float* b_hh   = (const float*)d_in[6];
    const float* W1     = (const float*)d_in[7];
    const float* b1     = (const float*)d_in[8];
    const float* W2     = (const float*)d_in[9];
    const float* b2     = (const float*)d_in[10];
    const float* W3     = (const float*)d_in[11];
    const float* b3     = (const float*)d_in[12];
    float* y    = (float*)d_out;
    float* outs = y + Y_SIZE;

    lstm_kernel<<<dim3(256), dim3(256), 0, stream>>>(x, h_init, c_init, W_ih, W_hh,
                                                     b_ih, b_hh, y);
    heads_kernel<<<dim3(2048), dim3(256), 0, stream>>>(y, W1, b1, W2, b2, W3, b3, outs);
}